// Round 4
// baseline (352.991 us; speedup 1.0000x reference)
//
#include <hip/hip_runtime.h>

#define NN 100000
#define NE 1200000
#define DD 64
#define NTILES 3125        // NN/32 exact
#define NBK 391            // buckets, 256 rows each (row>>8); NBK*256 = 100096
#define MLEN (NBK * 256)   // count-matrix length
#define EPB 4688           // ceil(NE/256) edges per bucket-pass block
#define ECAP 1024          // LDS edge-stage capacity per 32-node block (mean 384, sigma ~20)

typedef unsigned int uint32;
typedef unsigned char uint8;
typedef unsigned short ushort16;
typedef __attribute__((ext_vector_type(8))) short short8;    // 8 bf16 (4 VGPR)
typedef __attribute__((ext_vector_type(16))) float f32x16;   // MFMA 32x32 acc

__device__ __forceinline__ ushort16 f2bf(float x) {
    uint32 u = __float_as_uint(x);
    u += 0x7FFFu + ((u >> 16) & 1u);   // round-to-nearest-even
    return (ushort16)(u >> 16);
}
__device__ __forceinline__ float bflo(uint32 u) { return __uint_as_float(u << 16); }
__device__ __forceinline__ float bfhi(uint32 u) { return __uint_as_float(u & 0xFFFF0000u); }
__device__ __forceinline__ uint32 pack2(float a, float b) {
    return (uint32)f2bf(a) | ((uint32)f2bf(b) << 16);
}

// ---- Merged launch 1: bucket count (blocks 0..255) + W pre-pack (256..261)
//      + layer-1 GEMM (262..652, self-packs its W -> no intra-launch dep) --

__global__ __launch_bounds__(512)
void k_init(const int* __restrict__ row, int* __restrict__ M,
            const float* __restrict__ selfk, const float* __restrict__ neighk,
            short8* __restrict__ wpack, const float* __restrict__ x,
            ushort16* __restrict__ hs, ushort16* __restrict__ y,
            const float* __restrict__ biases) {
    if (blockIdx.x >= 262) {
        // ---- layer-1 GEMM: hs = x@Ws + b (bf16), y = x@Wn (bf16) ----
        int lane  = threadIdx.x & 63;
        int wave  = threadIdx.x >> 6;                  // 0..7
        int wid   = (blockIdx.x - 262) * 8 + wave;     // 0..3127
        int mrow  = lane & 31;
        int khalf = lane >> 5;
        int t     = wid & 1;

        short8 Wf[2][4];
        #pragma unroll
        for (int g = 0; g < 2; g++) {
            const float* W = g ? neighk : selfk;       // layer 0
            #pragma unroll
            for (int s = 0; s < 4; s++) {
                int k0 = s * 16 + khalf * 8;
                short8 v;
                #pragma unroll
                for (int j = 0; j < 8; j++)
                    v[j] = (short)f2bf(W[(k0 + j) * 64 + t * 32 + mrow]);
                Wf[g][s] = v;
            }
        }
        float bval = biases[t * 32 + mrow];

        for (int tile = wid >> 1; tile < NTILES; tile += 1564) {
            int n0 = tile * 32;
            const float4* hf4 = (const float4*)(x + (size_t)(n0 + mrow) * 64)
                                + khalf * 2;
            short8 A[4];
            #pragma unroll
            for (int s = 0; s < 4; s++) {
                float4 q0 = hf4[s * 4];
                float4 q1 = hf4[s * 4 + 1];
                short8 a;
                a[0] = (short)f2bf(q0.x); a[1] = (short)f2bf(q0.y);
                a[2] = (short)f2bf(q0.z); a[3] = (short)f2bf(q0.w);
                a[4] = (short)f2bf(q1.x); a[5] = (short)f2bf(q1.y);
                a[6] = (short)f2bf(q1.z); a[7] = (short)f2bf(q1.w);
                A[s] = a;
            }

            f32x16 acc0, acc1;
            #pragma unroll
            for (int r = 0; r < 16; r++) { acc0[r] = 0.f; acc1[r] = 0.f; }

            #pragma unroll
            for (int s = 0; s < 4; s++) {
                acc0 = __builtin_amdgcn_mfma_f32_32x32x16_bf16(A[s], Wf[0][s], acc0, 0, 0, 0);
                acc1 = __builtin_amdgcn_mfma_f32_32x32x16_bf16(A[s], Wf[1][s], acc1, 0, 0, 0);
            }

            int colbase = t * 32 + mrow;
            #pragma unroll
            for (int r = 0; r < 16; r++) {
                int rw = (r & 3) + 8 * (r >> 2) + 4 * khalf;
                int nn = n0 + rw;
                hs[nn * DD + colbase] = f2bf(acc0[r] + bval);
                y [nn * DD + colbase] = f2bf(acc1[r]);
            }
        }
        return;
    }
    if (blockIdx.x >= 256) {
        int tid = (blockIdx.x - 256) * 512 + threadIdx.x;   // 0..3071
        if (tid < 3 * 16 * 64) {
            int lane  = tid & 63;
            int frag  = (tid >> 6) & 15;
            int layer = tid >> 10;
            int g = frag >> 3;
            int t = (frag >> 2) & 1;
            int s = frag & 3;
            const float* W = (g ? neighk : selfk) + layer * 4096;
            int n = t * 32 + (lane & 31);
            int k0 = s * 16 + (lane >> 5) * 8;
            short8 v;
            #pragma unroll
            for (int j = 0; j < 8; j++) v[j] = (short)f2bf(W[(k0 + j) * 64 + n]);
            wpack[tid] = v;
        }
        return;
    }
    __shared__ int bins[NBK];
    for (int i = threadIdx.x; i < NBK; i += 512) bins[i] = 0;
    __syncthreads();
    int start = blockIdx.x * EPB;
    int end = min(start + EPB, NE);
    for (int e = start + (int)threadIdx.x; e < end; e += 512)
        atomicAdd(&bins[row[e] >> 8], 1);
    __syncthreads();
    for (int i = threadIdx.x; i < NBK; i += 512)
        M[i * 256 + blockIdx.x] = bins[i];
}

// ---- CSR build ----------------------------------------------------------

__global__ void k_scan1(const int* __restrict__ in, int* __restrict__ outx,
                        int* __restrict__ partials) {
    __shared__ int tmp[256];
    int t = threadIdx.x;
    int i = blockIdx.x * 256 + t;
    int v = (i < MLEN) ? in[i] : 0;
    tmp[t] = v;
    __syncthreads();
    #pragma unroll
    for (int off = 1; off < 256; off <<= 1) {
        int add = (t >= off) ? tmp[t - off] : 0;
        __syncthreads();
        tmp[t] += add;
        __syncthreads();
    }
    if (i < MLEN) outx[i] = tmp[t] - v;            // exclusive (within block)
    if (t == 255) partials[blockIdx.x] = tmp[255]; // block total (raw)
}

// Every bscatter block inline-scans the 391 raw bucket totals (9 LDS
// rounds); block 0 publishes the scan for k_build.
__global__ __launch_bounds__(512)
void k_bscatter(const int* __restrict__ row, const int* __restrict__ col,
                const float* __restrict__ ew, const int* __restrict__ Mscan,
                const int* __restrict__ partials, int* __restrict__ partials2,
                uint32* __restrict__ colw, uint8* __restrict__ rowlo) {
    __shared__ int tmp[512];
    __shared__ int cur[NBK];
    int t = threadIdx.x;
    int v = (t < NBK) ? partials[t] : 0;
    tmp[t] = v;
    __syncthreads();
    #pragma unroll
    for (int off = 1; off < 512; off <<= 1) {
        int add = (t >= off) ? tmp[t - off] : 0;
        __syncthreads();
        tmp[t] += add;
        __syncthreads();
    }
    if (t < NBK) {
        int excl = tmp[t] - v;
        cur[t] = Mscan[t * 256 + blockIdx.x] + excl;
        if (blockIdx.x == 0) partials2[t] = excl;
    }
    __syncthreads();
    int start = blockIdx.x * EPB;
    int end = min(start + EPB, NE);
    for (int e = start + (int)threadIdx.x; e < end; e += 512) {
        int r = row[e];
        int wq = (int)(ew[e] * 32767.0f + 0.5f);
        wq = (wq > 32767) ? 32767 : wq;
        int p = atomicAdd(&cur[r >> 8], 1);
        colw[p]  = ((uint32)col[e] << 15) | (uint32)wq;
        rowlo[p] = (uint8)(r & 255);
    }
}

__global__ __launch_bounds__(256)
void k_build(const int* __restrict__ Mscan, const int* __restrict__ partials2,
             const uint32* __restrict__ colw, const uint8* __restrict__ rowlo,
             uint32* __restrict__ edges, int* __restrict__ offsets) {
    __shared__ int bins[256];
    __shared__ int tmp[256];
    __shared__ int cur[256];
    int b = blockIdx.x;
    int t = threadIdx.x;
    int bstart = Mscan[b * 256] + partials2[b];
    int bend   = (b == NBK - 1) ? NE : Mscan[(b + 1) * 256] + partials2[b + 1];
    bins[t] = 0;
    __syncthreads();
    for (int p = bstart + t; p < bend; p += 256)
        atomicAdd(&bins[rowlo[p]], 1);
    __syncthreads();
    int v = bins[t];
    tmp[t] = v;
    __syncthreads();
    #pragma unroll
    for (int off = 1; off < 256; off <<= 1) {
        int add = (t >= off) ? tmp[t - off] : 0;
        __syncthreads();
        tmp[t] += add;
        __syncthreads();
    }
    int base = bstart + (tmp[t] - v);
    cur[t] = base;
    int rowid = b * 256 + t;
    if (rowid < NN) offsets[rowid] = base;
    if (b == 0 && t == 0) offsets[NN] = NE;
    __syncthreads();
    for (int p = bstart + t; p < bend; p += 256) {
        uint32 cw = colw[p];
        int dst = atomicAdd(&cur[rowlo[p]], 1);
        edges[dst] = cw;                 // block-private range: full lines
    }
}

// ---- Fused agg + next-layer GEMM ---------------------------------------
// R3 post-mortem: per-node group loops run to the MAX degree of 8 nodes
// per wave (E[max8 Poisson(12)] ~ 18 vs mean 12) -> ~1.5x wasted
// wave-iterations + masked lanes. New structure: the block's contiguous
// CSR edge range is processed FLAT -- 32 groups take equal chunks
// (ceil(m/32), balanced +-1 by construction). Edges are row-sorted, so
// each group register-accumulates over row-runs and flushes to a padded
// LDS f32 accumulator (stride 65 -> conflict-free ds_add_f32) only on
// row change. Self term pre-initializes the accumulator.

__global__ __launch_bounds__(256)
void agg_gemm(const uint4* __restrict__ hs4, const uint4* __restrict__ y4,
              ushort16* __restrict__ hs_out, ushort16* __restrict__ y_out,
              const int* __restrict__ offsets, const uint32* __restrict__ edges,
              const short8* __restrict__ wpack, const float* __restrict__ bias) {
    __shared__ __align__(16) uint32 ubuf[ECAP * 2];   // esh; reused as bf16 sh
    __shared__ float sacc[32 * 65];
    __shared__ int loff[33];
    uint2* esh = (uint2*)ubuf;
    int tid  = threadIdx.x;
    int lane = tid & 63;
    int wave = tid >> 6;
    int g  = lane >> 3;          // group-in-wave
    int fl = lane & 7;           // feature octet
    int n0 = blockIdx.x * 32;
    int lrow = wave * 8 + g;     // node-in-block == flat group id 0..31
    int n = n0 + lrow;

    if (tid < 33) loff[tid] = offsets[n0 + tid];
    // self-term init (f32) into the accumulator
    uint4 hv = hs4[n * 8 + fl];
    {
        float* ap = &sacc[lrow * 65 + fl * 8];
        ap[0] = bflo(hv.x); ap[1] = bfhi(hv.x);
        ap[2] = bflo(hv.y); ap[3] = bfhi(hv.y);
        ap[4] = bflo(hv.z); ap[5] = bfhi(hv.z);
        ap[6] = bflo(hv.w); ap[7] = bfhi(hv.w);
    }
    __syncthreads();

    int ebase = loff[0];
    int m  = loff[32] - ebase;
    int mm = min(m, ECAP);
    // stage + decode + 5-step binary-search row tag (low 5 bits of .x)
    for (int i = tid; i < mm; i += 256) {
        uint32 ed = edges[ebase + i];
        int gi = ebase + i;
        int lo = 0, hi = 32;
        #pragma unroll
        for (int st = 0; st < 5; st++) {
            int mid = (lo + hi) >> 1;
            if (loff[mid] <= gi) lo = mid; else hi = mid;
        }
        esh[i] = make_uint2(((ed >> 15) << 7) | (uint32)lo,
                            __float_as_uint((float)(ed & 32767u) * (1.0f / 32767.0f)));
    }
    __syncthreads();

    uint32 flB = (uint32)fl * 16u;
    const char* ybase = (const char*)y4;
    int chunk = (mm + 31) >> 5;
    int j0 = lrow * chunk;
    int j1 = min(j0 + chunk, mm);
    float r0=0.f,r1=0.f,r2=0.f,r3=0.f,r4=0.f,r5=0.f,r6=0.f,r7=0.f;
    int curr = -1;
    #pragma unroll 2
    for (int j = j0; j < j1; j++) {
        uint2 e = esh[j];
        int r = (int)(e.x & 31u);
        float w = __uint_as_float(e.y);
        uint4 yv = *(const uint4*)(ybase + ((e.x & 0xFFFFFF80u) + flB));
        if (r != curr) {
            if (curr >= 0) {
                float* p = &sacc[curr * 65 + fl * 8];
                atomicAdd(p+0, r0); atomicAdd(p+1, r1);
                atomicAdd(p+2, r2); atomicAdd(p+3, r3);
                atomicAdd(p+4, r4); atomicAdd(p+5, r5);
                atomicAdd(p+6, r6); atomicAdd(p+7, r7);
            }
            r0=r1=r2=r3=r4=r5=r6=r7=0.f;
            curr = r;
        }
        r0 = fmaf(bflo(yv.x), w, r0);
        r1 = fmaf(bfhi(yv.x), w, r1);
        r2 = fmaf(bflo(yv.y), w, r2);
        r3 = fmaf(bfhi(yv.y), w, r3);
        r4 = fmaf(bflo(yv.z), w, r4);
        r5 = fmaf(bfhi(yv.z), w, r5);
        r6 = fmaf(bflo(yv.w), w, r6);
        r7 = fmaf(bfhi(yv.w), w, r7);
    }
    if (curr >= 0) {
        float* p = &sacc[curr * 65 + fl * 8];
        atomicAdd(p+0, r0); atomicAdd(p+1, r1);
        atomicAdd(p+2, r2); atomicAdd(p+3, r3);
        atomicAdd(p+4, r4); atomicAdd(p+5, r5);
        atomicAdd(p+6, r6); atomicAdd(p+7, r7);
    }
    // rare overflow fallback (m > ECAP: ~32 sigma out, kept for safety)
    for (int i = ECAP + lrow; i < m; i += 32) {
        uint32 ed = edges[ebase + i];
        int gi = ebase + i;
        int lo = 0, hi = 32;
        for (int st = 0; st < 5; st++) {
            int mid = (lo + hi) >> 1;
            if (loff[mid] <= gi) lo = mid; else hi = mid;
        }
        float w = (float)(ed & 32767u) * (1.0f / 32767.0f);
        uint4 yv = *(const uint4*)(ybase + (((ed >> 15) << 7) + flB));
        float* p = &sacc[lo * 65 + fl * 8];
        atomicAdd(p+0, bflo(yv.x)*w); atomicAdd(p+1, bfhi(yv.x)*w);
        atomicAdd(p+2, bflo(yv.y)*w); atomicAdd(p+3, bfhi(yv.y)*w);
        atomicAdd(p+4, bflo(yv.z)*w); atomicAdd(p+5, bfhi(yv.z)*w);
        atomicAdd(p+6, bflo(yv.w)*w); atomicAdd(p+7, bfhi(yv.w)*w);
    }
    __syncthreads();

    // relu + bf16 pack into sh (reuses esh storage; esh is dead now)
    uint32* sh = ubuf;
    {
        float* q = &sacc[lrow * 65 + fl * 8];
        uint32* dstp = &sh[lrow * 36 + fl * 4];
        dstp[0] = pack2(fmaxf(q[0], 0.f), fmaxf(q[1], 0.f));
        dstp[1] = pack2(fmaxf(q[2], 0.f), fmaxf(q[3], 0.f));
        dstp[2] = pack2(fmaxf(q[4], 0.f), fmaxf(q[5], 0.f));
        dstp[3] = pack2(fmaxf(q[6], 0.f), fmaxf(q[7], 0.f));
    }
    __syncthreads();

    // gemm phase
    int mrow  = lane & 31;
    int khalf = lane >> 5;
    int gsel  = wave >> 1;       // 0=self(hs) 1=neigh(y)
    int t     = wave & 1;        // col half

    short8 Wf[4];
    #pragma unroll
    for (int ss = 0; ss < 4; ss++)
        Wf[ss] = wpack[(((gsel * 2 + t) * 4) + ss) * 64 + lane];

    short8 A[4];
    #pragma unroll
    for (int ss = 0; ss < 4; ss++)
        A[ss] = *(const short8*)&sh[mrow * 36 + ss * 8 + khalf * 4];   // 16B, aligned

    f32x16 acc;
    #pragma unroll
    for (int r = 0; r < 16; r++) acc[r] = 0.f;
    #pragma unroll
    for (int ss = 0; ss < 4; ss++)
        acc = __builtin_amdgcn_mfma_f32_32x32x16_bf16(A[ss], Wf[ss], acc, 0, 0, 0);

    float bval = gsel ? 0.f : bias[t * 32 + mrow];
    ushort16* dst = gsel ? y_out : hs_out;
    int colbase = t * 32 + mrow;
    #pragma unroll
    for (int r = 0; r < 16; r++) {
        int rw = (r & 3) + 8 * (r >> 2) + 4 * khalf;
        dst[(n0 + rw) * DD + colbase] = f2bf(acc[r] + bval);
    }
}

// ---- Final aggregate: out = relu(hs[n] + sum_j w_j * y[col_j]), f32 ----

__global__ __launch_bounds__(256)
void agg_final(const uint4* __restrict__ hs4, const uint4* __restrict__ y4,
               float4* __restrict__ out, const int* __restrict__ offsets,
               const uint32* __restrict__ edges) {
    __shared__ __align__(16) uint32 ubuf[ECAP * 2];
    __shared__ float sacc[32 * 65];
    __shared__ int loff[33];
    uint2* esh = (uint2*)ubuf;
    int tid  = threadIdx.x;
    int lane = tid & 63;
    int wave = tid >> 6;
    int g  = lane >> 3;
    int fl = lane & 7;
    int n0 = blockIdx.x * 32;
    int lrow = wave * 8 + g;
    int n = n0 + lrow;           // 3125*32 == NN exact

    if (tid < 33) loff[tid] = offsets[n0 + tid];
    uint4 hv = hs4[n * 8 + fl];
    {
        float* ap = &sacc[lrow * 65 + fl * 8];
        ap[0] = bflo(hv.x); ap[1] = bfhi(hv.x);
        ap[2] = bflo(hv.y); ap[3] = bfhi(hv.y);
        ap[4] = bflo(hv.z); ap[5] = bfhi(hv.z);
        ap[6] = bflo(hv.w); ap[7] = bfhi(hv.w);
    }
    __syncthreads();

    int ebase = loff[0];
    int m  = loff[32] - ebase;
    int mm = min(m, ECAP);
    for (int i = tid; i < mm; i += 256) {
        uint32 ed = edges[ebase + i];
        int gi = ebase + i;
        int lo = 0, hi = 32;
        #pragma unroll
        for (int st = 0; st < 5; st++) {
            int mid = (lo + hi) >> 1;
            if (loff[mid] <= gi) lo = mid; else hi = mid;
        }
        esh[i] = make_uint2(((ed >> 15) << 7) | (uint32)lo,
                            __float_as_uint((float)(ed & 32767u) * (1.0f / 32767.0f)));
    }
    __syncthreads();

    uint32 flB = (uint32)fl * 16u;
    const char* ybase = (const char*)y4;
    int chunk = (mm + 31) >> 5;
    int j0 = lrow * chunk;
    int j1 = min(j0 + chunk, mm);
    float r0=0.f,r1=0.f,r2=0.f,r3=0.f,r4=0.f,r5=0.f,r6=0.f,r7=0.f;
    int curr = -1;
    #pragma unroll 2
    for (int j = j0; j < j1; j++) {
        uint2 e = esh[j];
        int r = (int)(e.x & 31u);
        float w = __uint_as_float(e.y);
        uint4 yv = *(const uint4*)(ybase + ((e.x & 0xFFFFFF80u) + flB));
        if (r != curr) {
            if (curr >= 0) {
                float* p = &sacc[curr * 65 + fl * 8];
                atomicAdd(p+0, r0); atomicAdd(p+1, r1);
                atomicAdd(p+2, r2); atomicAdd(p+3, r3);
                atomicAdd(p+4, r4); atomicAdd(p+5, r5);
                atomicAdd(p+6, r6); atomicAdd(p+7, r7);
            }
            r0=r1=r2=r3=r4=r5=r6=r7=0.f;
            curr = r;
        }
        r0 = fmaf(bflo(yv.x), w, r0);
        r1 = fmaf(bfhi(yv.x), w, r1);
        r2 = fmaf(bflo(yv.y), w, r2);
        r3 = fmaf(bfhi(yv.y), w, r3);
        r4 = fmaf(bflo(yv.z), w, r4);
        r5 = fmaf(bfhi(yv.z), w, r5);
        r6 = fmaf(bflo(yv.w), w, r6);
        r7 = fmaf(bfhi(yv.w), w, r7);
    }
    if (curr >= 0) {
        float* p = &sacc[curr * 65 + fl * 8];
        atomicAdd(p+0, r0); atomicAdd(p+1, r1);
        atomicAdd(p+2, r2); atomicAdd(p+3, r3);
        atomicAdd(p+4, r4); atomicAdd(p+5, r5);
        atomicAdd(p+6, r6); atomicAdd(p+7, r7);
    }
    for (int i = ECAP + lrow; i < m; i += 32) {
        uint32 ed = edges[ebase + i];
        int gi = ebase + i;
        int lo = 0, hi = 32;
        for (int st = 0; st < 5; st++) {
            int mid = (lo + hi) >> 1;
            if (loff[mid] <= gi) lo = mid; else hi = mid;
        }
        float w = (float)(ed & 32767u) * (1.0f / 32767.0f);
        uint4 yv = *(const uint4*)(ybase + (((ed >> 15) << 7) + flB));
        float* p = &sacc[lo * 65 + fl * 8];
        atomicAdd(p+0, bflo(yv.x)*w); atomicAdd(p+1, bfhi(yv.x)*w);
        atomicAdd(p+2, bflo(yv.y)*w); atomicAdd(p+3, bfhi(yv.y)*w);
        atomicAdd(p+4, bflo(yv.z)*w); atomicAdd(p+5, bfhi(yv.z)*w);
        atomicAdd(p+6, bflo(yv.w)*w); atomicAdd(p+7, bfhi(yv.w)*w);
    }
    __syncthreads();

    float* q = &sacc[lrow * 65 + fl * 8];
    out[n * 16 + fl * 2]     = make_float4(fmaxf(q[0], 0.f), fmaxf(q[1], 0.f),
                                           fmaxf(q[2], 0.f), fmaxf(q[3], 0.f));
    out[n * 16 + fl * 2 + 1] = make_float4(fmaxf(q[4], 0.f), fmaxf(q[5], 0.f),
                                           fmaxf(q[6], 0.f), fmaxf(q[7], 0.f));
}

// ---- launch -------------------------------------------------------------

extern "C" void kernel_launch(void* const* d_in, const int* in_sizes, int n_in,
                              void* d_out, int out_size, void* d_ws, size_t ws_size,
                              hipStream_t stream) {
    const float* x      = (const float*)d_in[0];
    const int*   ei     = (const int*)d_in[1];
    const float* ew     = (const float*)d_in[2];
    const float* selfk  = (const float*)d_in[3];
    const float* neighk = (const float*)d_in[4];
    const float* biases = (const float*)d_in[5];
    float* out = (float*)d_out;

    char* w = (char*)d_ws;
    ushort16* hsA   = (ushort16*)w; w += (size_t)NN * DD * sizeof(ushort16);
    ushort16* yA    = (ushort16*)w; w += (size_t)NN * DD * sizeof(ushort16);
    ushort16* hsB   = (ushort16*)w; w += (size_t)NN * DD * sizeof(ushort16);
    ushort16* yB    = (ushort16*)w; w += (size_t)NN * DD * sizeof(ushort16);
    uint32* edges   = (uint32*)w;   w += (size_t)NE * sizeof(uint32);
    uint32* colwB   = (uint32*)w;   w += (size_t)NE * sizeof(uint32);
    uint8*  rowlo   = (uint8*)w;    w += (size_t)NE * sizeof(uint8);
    w = (char*)(((size_t)w + 255) & ~(size_t)255);
    int*    M       = (int*)w;      w += (size_t)MLEN * sizeof(int);
    int*    Mscan   = (int*)w;      w += (size_t)MLEN * sizeof(int);
    int*    offsets = (int*)w;      w += (size_t)(NN + 1) * sizeof(int);
    int*    partials= (int*)w;      w += 512 * sizeof(int);
    int*    partials2=(int*)w;      w += 512 * sizeof(int);
    short8* wpack   = (short8*)w;   w += (size_t)3 * 16 * 64 * sizeof(short8);

    const int* row = ei;
    const int* col = ei + NE;

    // 1: bucket count + wpack + layer-1 GEMM (independent work, one launch)
    k_init    <<<653, 512, 0, stream>>>(row, M, selfk, neighk, wpack,
                                        x, hsA, yA, biases);
    k_scan1   <<<NBK, 256, 0, stream>>>(M, Mscan, partials);
    k_bscatter<<<256, 512, 0, stream>>>(row, col, ew, Mscan, partials, partials2,
                                        colwB, rowlo);
    k_build   <<<NBK, 256, 0, stream>>>(Mscan, partials2, colwB, rowlo, edges, offsets);

    // agg(layer1) + GEMM(layer2): -> hsB, yB
    agg_gemm <<<NTILES, 256, 0, stream>>>((const uint4*)hsA, (const uint4*)yA,
                                          hsB, yB, offsets, edges,
                                          wpack + 1024, biases + 64);
    // agg(layer2) + GEMM(layer3): -> hsA, yA
    agg_gemm <<<NTILES, 256, 0, stream>>>((const uint4*)hsB, (const uint4*)yB,
                                          hsA, yA, offsets, edges,
                                          wpack + 2048, biases + 128);
    // final aggregate -> out (f32)
    agg_final<<<NTILES, 256, 0, stream>>>((const uint4*)hsA, (const uint4*)yA,
                                          (float4*)out, offsets, edges);
}

// Round 5
// 247.782 us; speedup vs baseline: 1.4246x; 1.4246x over previous
//
#include <hip/hip_runtime.h>

#define NN 100000
#define NE 1200000
#define DD 64
#define NTILES 3125        // NN/32 exact
#define NBK 391            // buckets, 256 rows each (row>>8); NBK*256 = 100096
#define MLEN (NBK * 256)   // count-matrix length
#define EPB 4688           // ceil(NE/256) edges per bucket-pass block
#define ECAP 768           // LDS edge-stage capacity per 32-node block (mean 384)

typedef unsigned int uint32;
typedef unsigned char uint8;
typedef unsigned short ushort16;
typedef __attribute__((ext_vector_type(8))) short short8;    // 8 bf16 (4 VGPR)
typedef __attribute__((ext_vector_type(16))) float f32x16;   // MFMA 32x32 acc

__device__ __forceinline__ ushort16 f2bf(float x) {
    uint32 u = __float_as_uint(x);
    u += 0x7FFFu + ((u >> 16) & 1u);   // round-to-nearest-even
    return (ushort16)(u >> 16);
}
__device__ __forceinline__ float bflo(uint32 u) { return __uint_as_float(u << 16); }
__device__ __forceinline__ float bfhi(uint32 u) { return __uint_as_float(u & 0xFFFF0000u); }
__device__ __forceinline__ uint32 pack2(float a, float b) {
    return (uint32)f2bf(a) | ((uint32)f2bf(b) << 16);
}

__device__ __forceinline__ void fma8(float* a, uint4 yv, float w) {
    a[0] = fmaf(bflo(yv.x), w, a[0]);
    a[1] = fmaf(bfhi(yv.x), w, a[1]);
    a[2] = fmaf(bflo(yv.y), w, a[2]);
    a[3] = fmaf(bfhi(yv.y), w, a[3]);
    a[4] = fmaf(bflo(yv.z), w, a[4]);
    a[5] = fmaf(bfhi(yv.z), w, a[5]);
    a[6] = fmaf(bflo(yv.w), w, a[6]);
    a[7] = fmaf(bfhi(yv.w), w, a[7]);
}

// ---- gather loop: explicit depth-8 software pipeline --------------------
// MLP experiment: R2's loop had unroll-4 (so R3's depth-4 was a null by
// construction). Little's law at ~650cy L3 latency says in-flight depth
// is the lever: 8 named slots, reload slot k for edge j+8+k before the
// fmas of edge j+k. Static slot names (rule #20: no runtime indexing).
__device__ __forceinline__ void agg_lds(float* a, int ls, int le, uint32 flB,
                                        const uint2* __restrict__ esh,
                                        const char* __restrict__ ybase) {
    int cnt = le - ls;
    if (cnt <= 0) return;
    uint4 v0, v1, v2, v3, v4, v5, v6, v7;
    float w0=0.f,w1=0.f,w2=0.f,w3=0.f,w4=0.f,w5=0.f,w6=0.f,w7=0.f;
    {              uint2 e = esh[ls];     w0 = __uint_as_float(e.y); v0 = *(const uint4*)(ybase + (e.x + flB)); }
    if (cnt > 1) { uint2 e = esh[ls + 1]; w1 = __uint_as_float(e.y); v1 = *(const uint4*)(ybase + (e.x + flB)); }
    if (cnt > 2) { uint2 e = esh[ls + 2]; w2 = __uint_as_float(e.y); v2 = *(const uint4*)(ybase + (e.x + flB)); }
    if (cnt > 3) { uint2 e = esh[ls + 3]; w3 = __uint_as_float(e.y); v3 = *(const uint4*)(ybase + (e.x + flB)); }
    if (cnt > 4) { uint2 e = esh[ls + 4]; w4 = __uint_as_float(e.y); v4 = *(const uint4*)(ybase + (e.x + flB)); }
    if (cnt > 5) { uint2 e = esh[ls + 5]; w5 = __uint_as_float(e.y); v5 = *(const uint4*)(ybase + (e.x + flB)); }
    if (cnt > 6) { uint2 e = esh[ls + 6]; w6 = __uint_as_float(e.y); v6 = *(const uint4*)(ybase + (e.x + flB)); }
    if (cnt > 7) { uint2 e = esh[ls + 7]; w7 = __uint_as_float(e.y); v7 = *(const uint4*)(ybase + (e.x + flB)); }
    int j = ls;
    for (; j + 16 <= le; j += 8) {
        uint4 c; float u;
        c = v0; u = w0; { uint2 e = esh[j +  8]; w0 = __uint_as_float(e.y); v0 = *(const uint4*)(ybase + (e.x + flB)); } fma8(a, c, u);
        c = v1; u = w1; { uint2 e = esh[j +  9]; w1 = __uint_as_float(e.y); v1 = *(const uint4*)(ybase + (e.x + flB)); } fma8(a, c, u);
        c = v2; u = w2; { uint2 e = esh[j + 10]; w2 = __uint_as_float(e.y); v2 = *(const uint4*)(ybase + (e.x + flB)); } fma8(a, c, u);
        c = v3; u = w3; { uint2 e = esh[j + 11]; w3 = __uint_as_float(e.y); v3 = *(const uint4*)(ybase + (e.x + flB)); } fma8(a, c, u);
        c = v4; u = w4; { uint2 e = esh[j + 12]; w4 = __uint_as_float(e.y); v4 = *(const uint4*)(ybase + (e.x + flB)); } fma8(a, c, u);
        c = v5; u = w5; { uint2 e = esh[j + 13]; w5 = __uint_as_float(e.y); v5 = *(const uint4*)(ybase + (e.x + flB)); } fma8(a, c, u);
        c = v6; u = w6; { uint2 e = esh[j + 14]; w6 = __uint_as_float(e.y); v6 = *(const uint4*)(ybase + (e.x + flB)); } fma8(a, c, u);
        c = v7; u = w7; { uint2 e = esh[j + 15]; w7 = __uint_as_float(e.y); v7 = *(const uint4*)(ybase + (e.x + flB)); } fma8(a, c, u);
    }
    int r = le - j;                 // in [8..15] when cnt>=16, else == cnt
    if (r > 0) fma8(a, v0, w0);
    if (r > 1) fma8(a, v1, w1);
    if (r > 2) fma8(a, v2, w2);
    if (r > 3) fma8(a, v3, w3);
    if (r > 4) fma8(a, v4, w4);
    if (r > 5) fma8(a, v5, w5);
    if (r > 6) fma8(a, v6, w6);
    if (r > 7) fma8(a, v7, w7);
    for (int i = j + 8; i < le; i++) {   // up to 7 un-prefetched leftovers
        uint2 e = esh[i];
        uint4 yv = *(const uint4*)(ybase + (e.x + flB));
        fma8(a, yv, __uint_as_float(e.y));
    }
}

// Cold fallback if a 32-node block exceeds ECAP edges: decode from global.
__device__ __forceinline__ void agg_glob(float* a, int s, int e, uint32 flB,
                                         const uint32* __restrict__ edges,
                                         const char* __restrict__ ybase) {
    for (int j = s; j < e; j++) {
        uint32 ed = edges[j];
        float w = (float)(ed & 32767u) * (1.0f / 32767.0f);
        uint4 yv = *(const uint4*)(ybase + (((ed >> 15) << 7) + flB));
        fma8(a, yv, w);
    }
}

// ---- Merged launch 1: bucket count (blocks 0..255) + W pre-pack (256..261)
//      + layer-1 GEMM (262..652, self-packs its W -> no intra-launch dep) --

__global__ __launch_bounds__(512)
void k_init(const int* __restrict__ row, int* __restrict__ M,
            const float* __restrict__ selfk, const float* __restrict__ neighk,
            short8* __restrict__ wpack, const float* __restrict__ x,
            ushort16* __restrict__ hs, ushort16* __restrict__ y,
            const float* __restrict__ biases) {
    if (blockIdx.x >= 262) {
        // ---- layer-1 GEMM: hs = x@Ws + b (bf16), y = x@Wn (bf16) ----
        int lane  = threadIdx.x & 63;
        int wave  = threadIdx.x >> 6;                  // 0..7
        int wid   = (blockIdx.x - 262) * 8 + wave;     // 0..3127
        int mrow  = lane & 31;
        int khalf = lane >> 5;
        int t     = wid & 1;

        short8 Wf[2][4];
        #pragma unroll
        for (int g = 0; g < 2; g++) {
            const float* W = g ? neighk : selfk;       // layer 0
            #pragma unroll
            for (int s = 0; s < 4; s++) {
                int k0 = s * 16 + khalf * 8;
                short8 v;
                #pragma unroll
                for (int j = 0; j < 8; j++)
                    v[j] = (short)f2bf(W[(k0 + j) * 64 + t * 32 + mrow]);
                Wf[g][s] = v;
            }
        }
        float bval = biases[t * 32 + mrow];

        for (int tile = wid >> 1; tile < NTILES; tile += 1564) {
            int n0 = tile * 32;
            const float4* hf4 = (const float4*)(x + (size_t)(n0 + mrow) * 64)
                                + khalf * 2;
            short8 A[4];
            #pragma unroll
            for (int s = 0; s < 4; s++) {
                float4 q0 = hf4[s * 4];
                float4 q1 = hf4[s * 4 + 1];
                short8 a;
                a[0] = (short)f2bf(q0.x); a[1] = (short)f2bf(q0.y);
                a[2] = (short)f2bf(q0.z); a[3] = (short)f2bf(q0.w);
                a[4] = (short)f2bf(q1.x); a[5] = (short)f2bf(q1.y);
                a[6] = (short)f2bf(q1.z); a[7] = (short)f2bf(q1.w);
                A[s] = a;
            }

            f32x16 acc0, acc1;
            #pragma unroll
            for (int r = 0; r < 16; r++) { acc0[r] = 0.f; acc1[r] = 0.f; }

            #pragma unroll
            for (int s = 0; s < 4; s++) {
                acc0 = __builtin_amdgcn_mfma_f32_32x32x16_bf16(A[s], Wf[0][s], acc0, 0, 0, 0);
                acc1 = __builtin_amdgcn_mfma_f32_32x32x16_bf16(A[s], Wf[1][s], acc1, 0, 0, 0);
            }

            int colbase = t * 32 + mrow;
            #pragma unroll
            for (int r = 0; r < 16; r++) {
                int rw = (r & 3) + 8 * (r >> 2) + 4 * khalf;
                int nn = n0 + rw;
                hs[nn * DD + colbase] = f2bf(acc0[r] + bval);
                y [nn * DD + colbase] = f2bf(acc1[r]);
            }
        }
        return;
    }
    if (blockIdx.x >= 256) {
        int tid = (blockIdx.x - 256) * 512 + threadIdx.x;   // 0..3071
        if (tid < 3 * 16 * 64) {
            int lane  = tid & 63;
            int frag  = (tid >> 6) & 15;
            int layer = tid >> 10;
            int g = frag >> 3;
            int t = (frag >> 2) & 1;
            int s = frag & 3;
            const float* W = (g ? neighk : selfk) + layer * 4096;
            int n = t * 32 + (lane & 31);
            int k0 = s * 16 + (lane >> 5) * 8;
            short8 v;
            #pragma unroll
            for (int j = 0; j < 8; j++) v[j] = (short)f2bf(W[(k0 + j) * 64 + n]);
            wpack[tid] = v;
        }
        return;
    }
    __shared__ int bins[NBK];
    for (int i = threadIdx.x; i < NBK; i += 512) bins[i] = 0;
    __syncthreads();
    int start = blockIdx.x * EPB;
    int end = min(start + EPB, NE);
    for (int e = start + (int)threadIdx.x; e < end; e += 512)
        atomicAdd(&bins[row[e] >> 8], 1);
    __syncthreads();
    for (int i = threadIdx.x; i < NBK; i += 512)
        M[i * 256 + blockIdx.x] = bins[i];
}

// ---- CSR build ----------------------------------------------------------

__global__ void k_scan1(const int* __restrict__ in, int* __restrict__ outx,
                        int* __restrict__ partials) {
    __shared__ int tmp[256];
    int t = threadIdx.x;
    int i = blockIdx.x * 256 + t;
    int v = (i < MLEN) ? in[i] : 0;
    tmp[t] = v;
    __syncthreads();
    #pragma unroll
    for (int off = 1; off < 256; off <<= 1) {
        int add = (t >= off) ? tmp[t - off] : 0;
        __syncthreads();
        tmp[t] += add;
        __syncthreads();
    }
    if (i < MLEN) outx[i] = tmp[t] - v;            // exclusive (within block)
    if (t == 255) partials[blockIdx.x] = tmp[255]; // block total (raw)
}

// Every bscatter block inline-scans the 391 raw bucket totals (9 LDS
// rounds); block 0 publishes the scan for k_build.
__global__ __launch_bounds__(512)
void k_bscatter(const int* __restrict__ row, const int* __restrict__ col,
                const float* __restrict__ ew, const int* __restrict__ Mscan,
                const int* __restrict__ partials, int* __restrict__ partials2,
                uint32* __restrict__ colw, uint8* __restrict__ rowlo) {
    __shared__ int tmp[512];
    __shared__ int cur[NBK];
    int t = threadIdx.x;
    int v = (t < NBK) ? partials[t] : 0;
    tmp[t] = v;
    __syncthreads();
    #pragma unroll
    for (int off = 1; off < 512; off <<= 1) {
        int add = (t >= off) ? tmp[t - off] : 0;
        __syncthreads();
        tmp[t] += add;
        __syncthreads();
    }
    if (t < NBK) {
        int excl = tmp[t] - v;
        cur[t] = Mscan[t * 256 + blockIdx.x] + excl;
        if (blockIdx.x == 0) partials2[t] = excl;
    }
    __syncthreads();
    int start = blockIdx.x * EPB;
    int end = min(start + EPB, NE);
    for (int e = start + (int)threadIdx.x; e < end; e += 512) {
        int r = row[e];
        int wq = (int)(ew[e] * 32767.0f + 0.5f);
        wq = (wq > 32767) ? 32767 : wq;
        int p = atomicAdd(&cur[r >> 8], 1);
        colw[p]  = ((uint32)col[e] << 15) | (uint32)wq;
        rowlo[p] = (uint8)(r & 255);
    }
}

__global__ __launch_bounds__(256)
void k_build(const int* __restrict__ Mscan, const int* __restrict__ partials2,
             const uint32* __restrict__ colw, const uint8* __restrict__ rowlo,
             uint32* __restrict__ edges, int* __restrict__ offsets) {
    __shared__ int bins[256];
    __shared__ int tmp[256];
    __shared__ int cur[256];
    int b = blockIdx.x;
    int t = threadIdx.x;
    int bstart = Mscan[b * 256] + partials2[b];
    int bend   = (b == NBK - 1) ? NE : Mscan[(b + 1) * 256] + partials2[b + 1];
    bins[t] = 0;
    __syncthreads();
    for (int p = bstart + t; p < bend; p += 256)
        atomicAdd(&bins[rowlo[p]], 1);
    __syncthreads();
    int v = bins[t];
    tmp[t] = v;
    __syncthreads();
    #pragma unroll
    for (int off = 1; off < 256; off <<= 1) {
        int add = (t >= off) ? tmp[t - off] : 0;
        __syncthreads();
        tmp[t] += add;
        __syncthreads();
    }
    int base = bstart + (tmp[t] - v);
    cur[t] = base;
    int rowid = b * 256 + t;
    if (rowid < NN) offsets[rowid] = base;
    if (b == 0 && t == 0) offsets[NN] = NE;
    __syncthreads();
    for (int p = bstart + t; p < bend; p += 256) {
        uint32 cw = colw[p];
        int dst = atomicAdd(&cur[rowlo[p]], 1);
        edges[dst] = cw;                 // block-private range: full lines
    }
}

// ---- Fused agg + next-layer GEMM ---------------------------------------
// Block = 32 nodes = 4 waves x 8 nodes (8-lane group per node, lane owns
// 8 feats). Block prologue pre-decodes its contiguous CSR edge range into
// LDS (coalesced); hot loop is LDS-fed + depth-8 pipelined, y gathered as
// bf16 (128 B/edge). h packed bf16 into LDS (stride 36 uints). Gemm
// phase: wave = gsel*2 + t, 4 MFMA.

__global__ __launch_bounds__(256)
void agg_gemm(const uint4* __restrict__ hs4, const uint4* __restrict__ y4,
              ushort16* __restrict__ hs_out, ushort16* __restrict__ y_out,
              const int* __restrict__ offsets, const uint32* __restrict__ edges,
              const short8* __restrict__ wpack, const float* __restrict__ bias) {
    __shared__ uint32 sh[32 * 36];
    __shared__ uint2 esh[ECAP];
    int lane = threadIdx.x & 63;
    int wave = threadIdx.x >> 6;
    int g  = lane >> 3;          // group 0..7 -> node
    int fl = lane & 7;           // feature octet
    int n0 = blockIdx.x * 32;
    int lrow = wave * 8 + g;     // 0..31
    int n = n0 + lrow;

    int ebase = offsets[n0];
    int m = min(offsets[n0 + 32] - ebase, ECAP);
    for (int i = threadIdx.x; i < m; i += 256) {
        uint32 ed = edges[ebase + i];
        esh[i] = make_uint2((ed >> 15) << 7,
                            __float_as_uint((float)(ed & 32767u) * (1.0f / 32767.0f)));
    }
    int s = offsets[n];
    int e = offsets[n + 1];
    uint4 hv = hs4[n * 8 + fl];
    __syncthreads();

    float a[8] = {bflo(hv.x), bfhi(hv.x), bflo(hv.y), bfhi(hv.y),
                  bflo(hv.z), bfhi(hv.z), bflo(hv.w), bfhi(hv.w)};
    uint32 flB = (uint32)fl * 16u;
    const char* ybase = (const char*)y4;
    int ls = s - ebase, le = e - ebase;
    agg_lds(a, min(ls, ECAP), min(le, ECAP), flB, esh, ybase);
    if (le > ECAP)
        agg_glob(a, ebase + max(ls, ECAP), ebase + le, flB, edges, ybase);

    uint32* dstp = &sh[lrow * 36 + fl * 4];
    dstp[0] = pack2(fmaxf(a[0], 0.f), fmaxf(a[1], 0.f));
    dstp[1] = pack2(fmaxf(a[2], 0.f), fmaxf(a[3], 0.f));
    dstp[2] = pack2(fmaxf(a[4], 0.f), fmaxf(a[5], 0.f));
    dstp[3] = pack2(fmaxf(a[6], 0.f), fmaxf(a[7], 0.f));
    __syncthreads();

    // gemm phase
    int mrow  = lane & 31;
    int khalf = lane >> 5;
    int gsel  = wave >> 1;       // 0=self(hs) 1=neigh(y)
    int t     = wave & 1;        // col half

    short8 Wf[4];
    #pragma unroll
    for (int ss = 0; ss < 4; ss++)
        Wf[ss] = wpack[(((gsel * 2 + t) * 4) + ss) * 64 + lane];

    short8 A[4];
    #pragma unroll
    for (int ss = 0; ss < 4; ss++)
        A[ss] = *(const short8*)&sh[mrow * 36 + ss * 8 + khalf * 4];   // 16B, aligned

    f32x16 acc;
    #pragma unroll
    for (int r = 0; r < 16; r++) acc[r] = 0.f;
    #pragma unroll
    for (int ss = 0; ss < 4; ss++)
        acc = __builtin_amdgcn_mfma_f32_32x32x16_bf16(A[ss], Wf[ss], acc, 0, 0, 0);

    float bval = gsel ? 0.f : bias[t * 32 + mrow];
    ushort16* dst = gsel ? y_out : hs_out;
    int colbase = t * 32 + mrow;
    #pragma unroll
    for (int r = 0; r < 16; r++) {
        int rw = (r & 3) + 8 * (r >> 2) + 4 * khalf;
        dst[(n0 + rw) * DD + colbase] = f2bf(acc[r] + bval);
    }
}

// ---- Final aggregate: out = relu(hs[n] + sum_j w_j * y[col_j]), f32 ----

__global__ __launch_bounds__(256)
void agg_final(const uint4* __restrict__ hs4, const uint4* __restrict__ y4,
               float4* __restrict__ out, const int* __restrict__ offsets,
               const uint32* __restrict__ edges) {
    __shared__ uint2 esh[ECAP];
    int lane = threadIdx.x & 63;
    int wave = threadIdx.x >> 6;
    int g  = lane >> 3;
    int fl = lane & 7;
    int n0 = blockIdx.x * 32;
    int n = n0 + wave * 8 + g;   // 3125*32 == NN exact

    int ebase = offsets[n0];
    int m = min(offsets[n0 + 32] - ebase, ECAP);
    for (int i = threadIdx.x; i < m; i += 256) {
        uint32 ed = edges[ebase + i];
        esh[i] = make_uint2((ed >> 15) << 7,
                            __float_as_uint((float)(ed & 32767u) * (1.0f / 32767.0f)));
    }
    int s = offsets[n];
    int e = offsets[n + 1];
    uint4 hv = hs4[n * 8 + fl];
    __syncthreads();

    float a[8] = {bflo(hv.x), bfhi(hv.x), bflo(hv.y), bfhi(hv.y),
                  bflo(hv.z), bfhi(hv.z), bflo(hv.w), bfhi(hv.w)};
    uint32 flB = (uint32)fl * 16u;
    const char* ybase = (const char*)y4;
    int ls = s - ebase, le = e - ebase;
    agg_lds(a, min(ls, ECAP), min(le, ECAP), flB, esh, ybase);
    if (le > ECAP)
        agg_glob(a, ebase + max(ls, ECAP), ebase + le, flB, edges, ybase);

    out[n * 16 + fl * 2]     = make_float4(fmaxf(a[0], 0.f), fmaxf(a[1], 0.f),
                                           fmaxf(a[2], 0.f), fmaxf(a[3], 0.f));
    out[n * 16 + fl * 2 + 1] = make_float4(fmaxf(a[4], 0.f), fmaxf(a[5], 0.f),
                                           fmaxf(a[6], 0.f), fmaxf(a[7], 0.f));
}

// ---- launch -------------------------------------------------------------

extern "C" void kernel_launch(void* const* d_in, const int* in_sizes, int n_in,
                              void* d_out, int out_size, void* d_ws, size_t ws_size,
                              hipStream_t stream) {
    const float* x      = (const float*)d_in[0];
    const int*   ei     = (const int*)d_in[1];
    const float* ew     = (const float*)d_in[2];
    const float* selfk  = (const float*)d_in[3];
    const float* neighk = (const float*)d_in[4];
    const float* biases = (const float*)d_in[5];
    float* out = (float*)d_out;

    char* w = (char*)d_ws;
    ushort16* hsA   = (ushort16*)w; w += (size_t)NN * DD * sizeof(ushort16);
    ushort16* yA    = (ushort16*)w; w += (size_t)NN * DD * sizeof(ushort16);
    ushort16* hsB   = (ushort16*)w; w += (size_t)NN * DD * sizeof(ushort16);
    ushort16* yB    = (ushort16*)w; w += (size_t)NN * DD * sizeof(ushort16);
    uint32* edges   = (uint32*)w;   w += (size_t)NE * sizeof(uint32);
    uint32* colwB   = (uint32*)w;   w += (size_t)NE * sizeof(uint32);
    uint8*  rowlo   = (uint8*)w;    w += (size_t)NE * sizeof(uint8);
    w = (char*)(((size_t)w + 255) & ~(size_t)255);
    int*    M       = (int*)w;      w += (size_t)MLEN * sizeof(int);
    int*    Mscan   = (int*)w;      w += (size_t)MLEN * sizeof(int);
    int*    offsets = (int*)w;      w += (size_t)(NN + 1) * sizeof(int);
    int*    partials= (int*)w;      w += 512 * sizeof(int);
    int*    partials2=(int*)w;      w += 512 * sizeof(int);
    short8* wpack   = (short8*)w;   w += (size_t)3 * 16 * 64 * sizeof(short8);

    const int* row = ei;
    const int* col = ei + NE;

    // 1: bucket count + wpack + layer-1 GEMM (independent work, one launch)
    k_init    <<<653, 512, 0, stream>>>(row, M, selfk, neighk, wpack,
                                        x, hsA, yA, biases);
    k_scan1   <<<NBK, 256, 0, stream>>>(M, Mscan, partials);
    k_bscatter<<<256, 512, 0, stream>>>(row, col, ew, Mscan, partials, partials2,
                                        colwB, rowlo);
    k_build   <<<NBK, 256, 0, stream>>>(Mscan, partials2, colwB, rowlo, edges, offsets);

    // agg(layer1) + GEMM(layer2): -> hsB, yB
    agg_gemm <<<NTILES, 256, 0, stream>>>((const uint4*)hsA, (const uint4*)yA,
                                          hsB, yB, offsets, edges,
                                          wpack + 1024, biases + 64);
    // agg(layer2) + GEMM(layer3): -> hsA, yA
    agg_gemm <<<NTILES, 256, 0, stream>>>((const uint4*)hsB, (const uint4*)yB,
                                          hsA, yA, offsets, edges,
                                          wpack + 2048, biases + 128);
    // final aggregate -> out (f32)
    agg_final<<<NTILES, 256, 0, stream>>>((const uint4*)hsA, (const uint4*)yA,
                                          (float4*)out, offsets, edges);
}

// Round 6
// 219.827 us; speedup vs baseline: 1.6058x; 1.1272x over previous
//
#include <hip/hip_runtime.h>

#define NN 100000
#define NE 1200000
#define DD 64
#define NTILES 3125        // NN/32 exact
#define NBK 391            // buckets, 256 rows each (row>>8); NBK*256 = 100096
#define MLEN (NBK * 256)   // count-matrix length
#define EPB 4688           // ceil(NE/256) edges per bucket-pass block
#define ECAP 768           // LDS edge-stage capacity per 32-node block (mean 384)

typedef unsigned int uint32;
typedef unsigned char uint8;
typedef unsigned short ushort16;
typedef __attribute__((ext_vector_type(8))) short short8;    // 8 bf16 (4 VGPR)
typedef __attribute__((ext_vector_type(16))) float f32x16;   // MFMA 32x32 acc

__device__ __forceinline__ ushort16 f2bf(float x) {
    uint32 u = __float_as_uint(x);
    u += 0x7FFFu + ((u >> 16) & 1u);   // round-to-nearest-even
    return (ushort16)(u >> 16);
}
__device__ __forceinline__ float bflo(uint32 u) { return __uint_as_float(u << 16); }
__device__ __forceinline__ float bfhi(uint32 u) { return __uint_as_float(u & 0xFFFF0000u); }
__device__ __forceinline__ uint32 pack2(float a, float b) {
    return (uint32)f2bf(a) | ((uint32)f2bf(b) << 16);
}

// ---- gather loop (R2-proven: plain unroll-4, VGPR~40, occupancy ~47%) ---
// R5 showed waves*depth is plateaued (~60 in flight); the lever left is
// AVERAGE LATENCY, attacked via col-range edge ordering (see k_build).
__device__ __forceinline__ void agg_lds(float* a, int ls, int le, uint32 flB,
                                        const uint2* __restrict__ esh,
                                        const char* __restrict__ ybase) {
    #pragma unroll 4
    for (int j = ls; j < le; j++) {
        uint2 ei = esh[j];                       // (col*128, w bits)
        float w = __uint_as_float(ei.y);
        uint4 yv = *(const uint4*)(ybase + (ei.x + flB));
        a[0] = fmaf(bflo(yv.x), w, a[0]);
        a[1] = fmaf(bfhi(yv.x), w, a[1]);
        a[2] = fmaf(bflo(yv.y), w, a[2]);
        a[3] = fmaf(bfhi(yv.y), w, a[3]);
        a[4] = fmaf(bflo(yv.z), w, a[4]);
        a[5] = fmaf(bfhi(yv.z), w, a[5]);
        a[6] = fmaf(bflo(yv.w), w, a[6]);
        a[7] = fmaf(bfhi(yv.w), w, a[7]);
    }
}

// Cold fallback if a 32-node block exceeds ECAP edges: decode from global.
__device__ __forceinline__ void agg_glob(float* a, int s, int e, uint32 flB,
                                         const uint32* __restrict__ edges,
                                         const char* __restrict__ ybase) {
    for (int j = s; j < e; j++) {
        uint32 ed = edges[j];
        float w = (float)(ed & 32767u) * (1.0f / 32767.0f);
        uint4 yv = *(const uint4*)(ybase + (((ed >> 15) << 7) + flB));
        a[0] = fmaf(bflo(yv.x), w, a[0]);
        a[1] = fmaf(bfhi(yv.x), w, a[1]);
        a[2] = fmaf(bflo(yv.y), w, a[2]);
        a[3] = fmaf(bfhi(yv.y), w, a[3]);
        a[4] = fmaf(bflo(yv.z), w, a[4]);
        a[5] = fmaf(bfhi(yv.z), w, a[5]);
        a[6] = fmaf(bflo(yv.w), w, a[6]);
        a[7] = fmaf(bfhi(yv.w), w, a[7]);
    }
}

// ---- Merged launch 1: bucket count (blocks 0..255) + W pre-pack (256..261)
//      + layer-1 GEMM (262..652, self-packs its W -> no intra-launch dep) --

__global__ __launch_bounds__(512)
void k_init(const int* __restrict__ row, int* __restrict__ M,
            const float* __restrict__ selfk, const float* __restrict__ neighk,
            short8* __restrict__ wpack, const float* __restrict__ x,
            ushort16* __restrict__ hs, ushort16* __restrict__ y,
            const float* __restrict__ biases) {
    if (blockIdx.x >= 262) {
        // ---- layer-1 GEMM: hs = x@Ws + b (bf16), y = x@Wn (bf16) ----
        int lane  = threadIdx.x & 63;
        int wave  = threadIdx.x >> 6;                  // 0..7
        int wid   = (blockIdx.x - 262) * 8 + wave;     // 0..3127
        int mrow  = lane & 31;
        int khalf = lane >> 5;
        int t     = wid & 1;

        short8 Wf[2][4];
        #pragma unroll
        for (int g = 0; g < 2; g++) {
            const float* W = g ? neighk : selfk;       // layer 0
            #pragma unroll
            for (int s = 0; s < 4; s++) {
                int k0 = s * 16 + khalf * 8;
                short8 v;
                #pragma unroll
                for (int j = 0; j < 8; j++)
                    v[j] = (short)f2bf(W[(k0 + j) * 64 + t * 32 + mrow]);
                Wf[g][s] = v;
            }
        }
        float bval = biases[t * 32 + mrow];

        for (int tile = wid >> 1; tile < NTILES; tile += 1564) {
            int n0 = tile * 32;
            const float4* hf4 = (const float4*)(x + (size_t)(n0 + mrow) * 64)
                                + khalf * 2;
            short8 A[4];
            #pragma unroll
            for (int s = 0; s < 4; s++) {
                float4 q0 = hf4[s * 4];
                float4 q1 = hf4[s * 4 + 1];
                short8 a;
                a[0] = (short)f2bf(q0.x); a[1] = (short)f2bf(q0.y);
                a[2] = (short)f2bf(q0.z); a[3] = (short)f2bf(q0.w);
                a[4] = (short)f2bf(q1.x); a[5] = (short)f2bf(q1.y);
                a[6] = (short)f2bf(q1.z); a[7] = (short)f2bf(q1.w);
                A[s] = a;
            }

            f32x16 acc0, acc1;
            #pragma unroll
            for (int r = 0; r < 16; r++) { acc0[r] = 0.f; acc1[r] = 0.f; }

            #pragma unroll
            for (int s = 0; s < 4; s++) {
                acc0 = __builtin_amdgcn_mfma_f32_32x32x16_bf16(A[s], Wf[0][s], acc0, 0, 0, 0);
                acc1 = __builtin_amdgcn_mfma_f32_32x32x16_bf16(A[s], Wf[1][s], acc1, 0, 0, 0);
            }

            int colbase = t * 32 + mrow;
            #pragma unroll
            for (int r = 0; r < 16; r++) {
                int rw = (r & 3) + 8 * (r >> 2) + 4 * khalf;
                int nn = n0 + rw;
                hs[nn * DD + colbase] = f2bf(acc0[r] + bval);
                y [nn * DD + colbase] = f2bf(acc1[r]);
            }
        }
        return;
    }
    if (blockIdx.x >= 256) {
        int tid = (blockIdx.x - 256) * 512 + threadIdx.x;   // 0..3071
        if (tid < 3 * 16 * 64) {
            int lane  = tid & 63;
            int frag  = (tid >> 6) & 15;
            int layer = tid >> 10;
            int g = frag >> 3;
            int t = (frag >> 2) & 1;
            int s = frag & 3;
            const float* W = (g ? neighk : selfk) + layer * 4096;
            int n = t * 32 + (lane & 31);
            int k0 = s * 16 + (lane >> 5) * 8;
            short8 v;
            #pragma unroll
            for (int j = 0; j < 8; j++) v[j] = (short)f2bf(W[(k0 + j) * 64 + n]);
            wpack[tid] = v;
        }
        return;
    }
    __shared__ int bins[NBK];
    for (int i = threadIdx.x; i < NBK; i += 512) bins[i] = 0;
    __syncthreads();
    int start = blockIdx.x * EPB;
    int end = min(start + EPB, NE);
    for (int e = start + (int)threadIdx.x; e < end; e += 512)
        atomicAdd(&bins[row[e] >> 8], 1);
    __syncthreads();
    for (int i = threadIdx.x; i < NBK; i += 512)
        M[i * 256 + blockIdx.x] = bins[i];
}

// ---- CSR build ----------------------------------------------------------

__global__ void k_scan1(const int* __restrict__ in, int* __restrict__ outx,
                        int* __restrict__ partials) {
    __shared__ int tmp[256];
    int t = threadIdx.x;
    int i = blockIdx.x * 256 + t;
    int v = (i < MLEN) ? in[i] : 0;
    tmp[t] = v;
    __syncthreads();
    #pragma unroll
    for (int off = 1; off < 256; off <<= 1) {
        int add = (t >= off) ? tmp[t - off] : 0;
        __syncthreads();
        tmp[t] += add;
        __syncthreads();
    }
    if (i < MLEN) outx[i] = tmp[t] - v;            // exclusive (within block)
    if (t == 255) partials[blockIdx.x] = tmp[255]; // block total (raw)
}

// Every bscatter block inline-scans the 391 raw bucket totals (9 LDS
// rounds); block 0 publishes the scan for k_build.
__global__ __launch_bounds__(512)
void k_bscatter(const int* __restrict__ row, const int* __restrict__ col,
                const float* __restrict__ ew, const int* __restrict__ Mscan,
                const int* __restrict__ partials, int* __restrict__ partials2,
                uint32* __restrict__ colw, uint8* __restrict__ rowlo) {
    __shared__ int tmp[512];
    __shared__ int cur[NBK];
    int t = threadIdx.x;
    int v = (t < NBK) ? partials[t] : 0;
    tmp[t] = v;
    __syncthreads();
    #pragma unroll
    for (int off = 1; off < 512; off <<= 1) {
        int add = (t >= off) ? tmp[t - off] : 0;
        __syncthreads();
        tmp[t] += add;
        __syncthreads();
    }
    if (t < NBK) {
        int excl = tmp[t] - v;
        cur[t] = Mscan[t * 256 + blockIdx.x] + excl;
        if (blockIdx.x == 0) partials2[t] = excl;
    }
    __syncthreads();
    int start = blockIdx.x * EPB;
    int end = min(start + EPB, NE);
    for (int e = start + (int)threadIdx.x; e < end; e += 512) {
        int r = row[e];
        int wq = (int)(ew[e] * 32767.0f + 0.5f);
        wq = (wq > 32767) ? 32767 : wq;
        int p = atomicAdd(&cur[r >> 8], 1);
        colw[p]  = ((uint32)col[e] << 15) | (uint32)wq;
        rowlo[p] = (uint8)(r & 255);
    }
}

// k_build: per-row counting sort extended to (row x 16 col-range) bins.
// Output edge order within each row is sorted by col>>13 (~800KB of y per
// range) -> during agg, all groups sweep col-space together; the
// concurrent access frontier fits per-XCD L2 (4 MiB) instead of
// scattering over the full 12.8 MB y table. Latency fix, zero byte/
// accuracy cost (summation reorder only).
__global__ __launch_bounds__(256)
void k_build(const int* __restrict__ Mscan, const int* __restrict__ partials2,
             const uint32* __restrict__ colw, const uint8* __restrict__ rowlo,
             uint32* __restrict__ edges, int* __restrict__ offsets) {
    __shared__ int bins[256 * 16];   // (rowlo, colrange) counters -> cursors
    __shared__ int tmp[256];
    int b = blockIdx.x;
    int t = threadIdx.x;
    int bstart = Mscan[b * 256] + partials2[b];
    int bend   = (b == NBK - 1) ? NE : Mscan[(b + 1) * 256] + partials2[b + 1];
    for (int k = t; k < 4096; k += 256) bins[k] = 0;
    __syncthreads();
    for (int p = bstart + t; p < bend; p += 256) {
        uint32 cw = colw[p];
        int cr = (int)(cw >> 28);          // col>>13, col<2^17 -> 0..12
        atomicAdd(&bins[rowlo[p] * 16 + cr], 1);
    }
    __syncthreads();
    // exclusive scan over the 4096 bins: 16 serial per thread + ladder
    int base16 = t * 16;
    int own = 0;
    #pragma unroll
    for (int k = 0; k < 16; k++) {
        int v = bins[base16 + k];
        bins[base16 + k] = own;
        own += v;
    }
    tmp[t] = own;
    __syncthreads();
    #pragma unroll
    for (int off = 1; off < 256; off <<= 1) {
        int add = (t >= off) ? tmp[t - off] : 0;
        __syncthreads();
        tmp[t] += add;
        __syncthreads();
    }
    int rowbase = bstart + (tmp[t] - own);   // exclusive prefix for this row
    #pragma unroll
    for (int k = 0; k < 16; k++) bins[base16 + k] += rowbase;
    int rowid = b * 256 + t;
    if (rowid < NN) offsets[rowid] = rowbase;
    if (b == 0 && t == 0) offsets[NN] = NE;
    __syncthreads();
    for (int p = bstart + t; p < bend; p += 256) {
        uint32 cw = colw[p];
        int cr = (int)(cw >> 28);
        int dst = atomicAdd(&bins[rowlo[p] * 16 + cr], 1);
        edges[dst] = cw;                 // block-private range: full lines
    }
}

// ---- Fused agg + next-layer GEMM ---------------------------------------
// Block = 32 nodes = 4 waves x 8 nodes (8-lane group per node, lane owns
// 8 feats). Block prologue pre-decodes its contiguous CSR edge range into
// LDS (coalesced); hot loop is LDS-fed, y gathered as bf16 (128 B/edge),
// edges col-range-ordered for L2-frontier locality. h packed bf16 into
// LDS (stride 36 uints). Gemm phase: wave = gsel*2 + t, 4 MFMA.

__global__ __launch_bounds__(256)
void agg_gemm(const uint4* __restrict__ hs4, const uint4* __restrict__ y4,
              ushort16* __restrict__ hs_out, ushort16* __restrict__ y_out,
              const int* __restrict__ offsets, const uint32* __restrict__ edges,
              const short8* __restrict__ wpack, const float* __restrict__ bias) {
    __shared__ uint32 sh[32 * 36];
    __shared__ uint2 esh[ECAP];
    int lane = threadIdx.x & 63;
    int wave = threadIdx.x >> 6;
    int g  = lane >> 3;          // group 0..7 -> node
    int fl = lane & 7;           // feature octet
    int n0 = blockIdx.x * 32;
    int lrow = wave * 8 + g;     // 0..31
    int n = n0 + lrow;

    int ebase = offsets[n0];
    int m = min(offsets[n0 + 32] - ebase, ECAP);
    for (int i = threadIdx.x; i < m; i += 256) {
        uint32 ed = edges[ebase + i];
        esh[i] = make_uint2((ed >> 15) << 7,
                            __float_as_uint((float)(ed & 32767u) * (1.0f / 32767.0f)));
    }
    int s = offsets[n];
    int e = offsets[n + 1];
    uint4 hv = hs4[n * 8 + fl];
    __syncthreads();

    float a[8] = {bflo(hv.x), bfhi(hv.x), bflo(hv.y), bfhi(hv.y),
                  bflo(hv.z), bfhi(hv.z), bflo(hv.w), bfhi(hv.w)};
    uint32 flB = (uint32)fl * 16u;
    const char* ybase = (const char*)y4;
    int ls = s - ebase, le = e - ebase;
    agg_lds(a, min(ls, ECAP), min(le, ECAP), flB, esh, ybase);
    if (le > ECAP)
        agg_glob(a, ebase + max(ls, ECAP), ebase + le, flB, edges, ybase);

    uint32* dstp = &sh[lrow * 36 + fl * 4];
    dstp[0] = pack2(fmaxf(a[0], 0.f), fmaxf(a[1], 0.f));
    dstp[1] = pack2(fmaxf(a[2], 0.f), fmaxf(a[3], 0.f));
    dstp[2] = pack2(fmaxf(a[4], 0.f), fmaxf(a[5], 0.f));
    dstp[3] = pack2(fmaxf(a[6], 0.f), fmaxf(a[7], 0.f));
    __syncthreads();

    // gemm phase
    int mrow  = lane & 31;
    int khalf = lane >> 5;
    int gsel  = wave >> 1;       // 0=self(hs) 1=neigh(y)
    int t     = wave & 1;        // col half

    short8 Wf[4];
    #pragma unroll
    for (int ss = 0; ss < 4; ss++)
        Wf[ss] = wpack[(((gsel * 2 + t) * 4) + ss) * 64 + lane];

    short8 A[4];
    #pragma unroll
    for (int ss = 0; ss < 4; ss++)
        A[ss] = *(const short8*)&sh[mrow * 36 + ss * 8 + khalf * 4];   // 16B, aligned

    f32x16 acc;
    #pragma unroll
    for (int r = 0; r < 16; r++) acc[r] = 0.f;
    #pragma unroll
    for (int ss = 0; ss < 4; ss++)
        acc = __builtin_amdgcn_mfma_f32_32x32x16_bf16(A[ss], Wf[ss], acc, 0, 0, 0);

    float bval = gsel ? 0.f : bias[t * 32 + mrow];
    ushort16* dst = gsel ? y_out : hs_out;
    int colbase = t * 32 + mrow;
    #pragma unroll
    for (int r = 0; r < 16; r++) {
        int rw = (r & 3) + 8 * (r >> 2) + 4 * khalf;
        dst[(n0 + rw) * DD + colbase] = f2bf(acc[r] + bval);
    }
}

// ---- Final aggregate: out = relu(hs[n] + sum_j w_j * y[col_j]), f32 ----

__global__ __launch_bounds__(256)
void agg_final(const uint4* __restrict__ hs4, const uint4* __restrict__ y4,
               float4* __restrict__ out, const int* __restrict__ offsets,
               const uint32* __restrict__ edges) {
    __shared__ uint2 esh[ECAP];
    int lane = threadIdx.x & 63;
    int wave = threadIdx.x >> 6;
    int g  = lane >> 3;
    int fl = lane & 7;
    int n0 = blockIdx.x * 32;
    int n = n0 + wave * 8 + g;   // 3125*32 == NN exact

    int ebase = offsets[n0];
    int m = min(offsets[n0 + 32] - ebase, ECAP);
    for (int i = threadIdx.x; i < m; i += 256) {
        uint32 ed = edges[ebase + i];
        esh[i] = make_uint2((ed >> 15) << 7,
                            __float_as_uint((float)(ed & 32767u) * (1.0f / 32767.0f)));
    }
    int s = offsets[n];
    int e = offsets[n + 1];
    uint4 hv = hs4[n * 8 + fl];
    __syncthreads();

    float a[8] = {bflo(hv.x), bfhi(hv.x), bflo(hv.y), bfhi(hv.y),
                  bflo(hv.z), bfhi(hv.z), bflo(hv.w), bfhi(hv.w)};
    uint32 flB = (uint32)fl * 16u;
    const char* ybase = (const char*)y4;
    int ls = s - ebase, le = e - ebase;
    agg_lds(a, min(ls, ECAP), min(le, ECAP), flB, esh, ybase);
    if (le > ECAP)
        agg_glob(a, ebase + max(ls, ECAP), ebase + le, flB, edges, ybase);

    out[n * 16 + fl * 2]     = make_float4(fmaxf(a[0], 0.f), fmaxf(a[1], 0.f),
                                           fmaxf(a[2], 0.f), fmaxf(a[3], 0.f));
    out[n * 16 + fl * 2 + 1] = make_float4(fmaxf(a[4], 0.f), fmaxf(a[5], 0.f),
                                           fmaxf(a[6], 0.f), fmaxf(a[7], 0.f));
}

// ---- launch -------------------------------------------------------------

extern "C" void kernel_launch(void* const* d_in, const int* in_sizes, int n_in,
                              void* d_out, int out_size, void* d_ws, size_t ws_size,
                              hipStream_t stream) {
    const float* x      = (const float*)d_in[0];
    const int*   ei     = (const int*)d_in[1];
    const float* ew     = (const float*)d_in[2];
    const float* selfk  = (const float*)d_in[3];
    const float* neighk = (const float*)d_in[4];
    const float* biases = (const float*)d_in[5];
    float* out = (float*)d_out;

    char* w = (char*)d_ws;
    ushort16* hsA   = (ushort16*)w; w += (size_t)NN * DD * sizeof(ushort16);
    ushort16* yA    = (ushort16*)w; w += (size_t)NN * DD * sizeof(ushort16);
    ushort16* hsB   = (ushort16*)w; w += (size_t)NN * DD * sizeof(ushort16);
    ushort16* yB    = (ushort16*)w; w += (size_t)NN * DD * sizeof(ushort16);
    uint32* edges   = (uint32*)w;   w += (size_t)NE * sizeof(uint32);
    uint32* colwB   = (uint32*)w;   w += (size_t)NE * sizeof(uint32);
    uint8*  rowlo   = (uint8*)w;    w += (size_t)NE * sizeof(uint8);
    w = (char*)(((size_t)w + 255) & ~(size_t)255);
    int*    M       = (int*)w;      w += (size_t)MLEN * sizeof(int);
    int*    Mscan   = (int*)w;      w += (size_t)MLEN * sizeof(int);
    int*    offsets = (int*)w;      w += (size_t)(NN + 1) * sizeof(int);
    int*    partials= (int*)w;      w += 512 * sizeof(int);
    int*    partials2=(int*)w;      w += 512 * sizeof(int);
    short8* wpack   = (short8*)w;   w += (size_t)3 * 16 * 64 * sizeof(short8);

    const int* row = ei;
    const int* col = ei + NE;

    // 1: bucket count + wpack + layer-1 GEMM (independent work, one launch)
    k_init    <<<653, 512, 0, stream>>>(row, M, selfk, neighk, wpack,
                                        x, hsA, yA, biases);
    k_scan1   <<<NBK, 256, 0, stream>>>(M, Mscan, partials);
    k_bscatter<<<256, 512, 0, stream>>>(row, col, ew, Mscan, partials, partials2,
                                        colwB, rowlo);
    k_build   <<<NBK, 256, 0, stream>>>(Mscan, partials2, colwB, rowlo, edges, offsets);

    // agg(layer1) + GEMM(layer2): -> hsB, yB
    agg_gemm <<<NTILES, 256, 0, stream>>>((const uint4*)hsA, (const uint4*)yA,
                                          hsB, yB, offsets, edges,
                                          wpack + 1024, biases + 64);
    // agg(layer2) + GEMM(layer3): -> hsA, yA
    agg_gemm <<<NTILES, 256, 0, stream>>>((const uint4*)hsB, (const uint4*)yB,
                                          hsA, yA, offsets, edges,
                                          wpack + 2048, biases + 128);
    // final aggregate -> out (f32)
    agg_final<<<NTILES, 256, 0, stream>>>((const uint4*)hsA, (const uint4*)yA,
                                          (float4*)out, offsets, edges);
}